// Round 7
// baseline (98.929 us; speedup 1.0000x reference)
//
#include <hip/hip_runtime.h>
#include <hip/hip_bf16.h>

// Problem constants: B=16, TV=128, TH=64, F=512, H=512, D=256
#define BB 16
#define TV 128
#define TH 64
#define FF 512
#define HH 512
#define DD 256

#define LOG2E2 2.8853900817779268f   // 2*log2(e): exp2(LOG2E2*x) = e^{2x}

typedef __attribute__((ext_vector_type(8))) short bf16x8;   // 8 bf16 = 4 VGPRs
typedef __attribute__((ext_vector_type(4))) float f32x4;

__device__ __forceinline__ float fast_exp2(float x) {
#if __has_builtin(__builtin_amdgcn_exp2f)
  return __builtin_amdgcn_exp2f(x);
#else
  return __expf(x * 0.6931471805599453f);
#endif
}
__device__ __forceinline__ float fast_rcp(float x) {
#if __has_builtin(__builtin_amdgcn_rcpf)
  return __builtin_amdgcn_rcpf(x);
#else
  return 1.0f / x;
#endif
}
__device__ __forceinline__ unsigned short f2bf(float x) {  // RNE fp32->bf16
  union { float f; unsigned u; } a; a.f = x;
  unsigned r = a.u + 0x7fffu + ((a.u >> 16) & 1u);
  return (unsigned short)(r >> 16);
}
__device__ __forceinline__ bf16x8 pack_bf8(float4 lo, float4 hi) {
  bf16x8 r;
  r[0] = (short)f2bf(lo.x); r[1] = (short)f2bf(lo.y);
  r[2] = (short)f2bf(lo.z); r[3] = (short)f2bf(lo.w);
  r[4] = (short)f2bf(hi.x); r[5] = (short)f2bf(hi.y);
  r[6] = (short)f2bf(hi.z); r[7] = (short)f2bf(hi.w);
  return r;
}

// ---------------------------------------------------------------------------
// MFMA dual-GEMM, fp32 inputs, self-contained (no convert pass).
// 192 blocks * 256 thr (4 waves).
//   blocks [0,128):   Wv2T[b][d][t] = (v @ W)^T-per-b * LOG2E2   (transposed)
//   blocks [128,192): Uh2[m][d]     = (h @ U + b) * LOG2E2       (row-major)
// Block tile 128m x 32n x 512k; wave owns 32m. 2x2 of mfma_f32_16x16x32_bf16.
// B-tile: staged once from fp32 W/U (coalesced rows), transposed+converted
//   into LDS BT[32][520] bf16 ([n][k], pad->520 so b128 frag reads are
//   16B-aligned and bank-spread). A-frags: 8 contiguous fp32 from global,
//   packed to bf16 in-register (RNE).
// C/D: col = l&15, row = (l>>4)*4 + reg   (m89-verified)
// ---------------------------------------------------------------------------
#define BT_STRIDE 520
__global__ __launch_bounds__(256) void mfma_gemm_kernel(
    const float* __restrict__ v, const float* __restrict__ h,
    const float* __restrict__ W, const float* __restrict__ U,
    const float* __restrict__ bias, float* __restrict__ Wv2T,
    float* __restrict__ Uh2) {
  __shared__ unsigned short BTs[32 * BT_STRIDE];  // 33 KB

  const int bid = blockIdx.x;
  const float* A;
  const float* Bsrc;
  int mt, nt;
  bool is_wv;
  if (bid < 128) {
    A = v; Bsrc = W; is_wv = true;
    mt = bid >> 3; nt = bid & 7;          // mt 0..15 (x128 m), nt 0..7 (x32 n)
  } else {
    const int b2 = bid - 128;
    A = h; Bsrc = U; is_wv = false;
    mt = b2 >> 3; nt = b2 & 7;            // mt 0..7 (x128 m)
  }
  const int tid  = threadIdx.x;
  const int wv   = tid >> 6;              // 0..3
  const int lane = tid & 63;
  const int m0   = mt * 128 + wv * 32;
  const int n0   = nt * 32;
  const int r16  = lane & 15;
  const int quad = lane >> 4;

  // ---- stage B-tile: 512k x 32n fp32 -> BT[n][k] bf16 (transpose+convert)
  {
    const int kr = tid >> 3;              // 0..31 (k within pass)
    const int c4 = (tid & 7) << 2;        // 0,4,..,28 (n within tile)
#pragma unroll 4
    for (int p = 0; p < 16; p++) {
      const int k = p * 32 + kr;
      float4 wrow = *(const float4*)&Bsrc[(size_t)k * 256 + n0 + c4];
      BTs[(c4 + 0) * BT_STRIDE + k] = f2bf(wrow.x);
      BTs[(c4 + 1) * BT_STRIDE + k] = f2bf(wrow.y);
      BTs[(c4 + 2) * BT_STRIDE + k] = f2bf(wrow.z);
      BTs[(c4 + 3) * BT_STRIDE + k] = f2bf(wrow.w);
    }
  }
  __syncthreads();

  // ---- K-loop: A from global fp32 (inline cvt), B from LDS ----
  const float* a0p = A + (size_t)(m0 + r16) * 512 + quad * 8;
  const float* a1p = a0p + 16 * 512;
  const unsigned short* bt0 = &BTs[r16 * BT_STRIDE + quad * 8];
  const unsigned short* bt1 = &BTs[(16 + r16) * BT_STRIDE + quad * 8];

  f32x4 acc00 = {0.f, 0.f, 0.f, 0.f};
  f32x4 acc01 = {0.f, 0.f, 0.f, 0.f};
  f32x4 acc10 = {0.f, 0.f, 0.f, 0.f};
  f32x4 acc11 = {0.f, 0.f, 0.f, 0.f};

#pragma unroll 4
  for (int kc = 0; kc < 16; kc++) {
    float4 a0lo = *(const float4*)(a0p + kc * 32);
    float4 a0hi = *(const float4*)(a0p + kc * 32 + 4);
    float4 a1lo = *(const float4*)(a1p + kc * 32);
    float4 a1hi = *(const float4*)(a1p + kc * 32 + 4);
    bf16x8 a0 = pack_bf8(a0lo, a0hi);
    bf16x8 a1 = pack_bf8(a1lo, a1hi);
    bf16x8 b0 = *(const bf16x8*)(bt0 + kc * 32);
    bf16x8 b1 = *(const bf16x8*)(bt1 + kc * 32);
    acc00 = __builtin_amdgcn_mfma_f32_16x16x32_bf16(a0, b0, acc00, 0, 0, 0);
    acc01 = __builtin_amdgcn_mfma_f32_16x16x32_bf16(a0, b1, acc01, 0, 0, 0);
    acc10 = __builtin_amdgcn_mfma_f32_16x16x32_bf16(a1, b0, acc10, 0, 0, 0);
    acc11 = __builtin_amdgcn_mfma_f32_16x16x32_bf16(a1, b1, acc11, 0, 0, 0);
  }

  if (is_wv) {
    // Wv2T[b][d][t], b = mt, t-base = (m0&127) + quad*4
    const int tb = (m0 & 127) + quad * 4;
    float* Wb = Wv2T + (size_t)mt * 32768;
    float4 s00, s01, s10, s11;
#pragma unroll
    for (int r = 0; r < 4; r++) {
      (&s00.x)[r] = acc00[r] * LOG2E2;
      (&s01.x)[r] = acc01[r] * LOG2E2;
      (&s10.x)[r] = acc10[r] * LOG2E2;
      (&s11.x)[r] = acc11[r] * LOG2E2;
    }
    *(float4*)&Wb[(size_t)(n0 + r16) * 128 + tb]           = s00;
    *(float4*)&Wb[(size_t)(n0 + r16) * 128 + tb + 16]      = s10;
    *(float4*)&Wb[(size_t)(n0 + 16 + r16) * 128 + tb]      = s01;
    *(float4*)&Wb[(size_t)(n0 + 16 + r16) * 128 + tb + 16] = s11;
  } else {
    const float bj0 = bias[n0 + r16];
    const float bj1 = bias[n0 + 16 + r16];
#pragma unroll
    for (int r = 0; r < 4; r++) {
      const int row0 = m0 + quad * 4 + r;
      Uh2[(size_t)row0 * 256 + n0 + r16]             = (acc00[r] + bj0) * LOG2E2;
      Uh2[(size_t)row0 * 256 + n0 + 16 + r16]        = (acc01[r] + bj1) * LOG2E2;
      Uh2[(size_t)(row0 + 16) * 256 + n0 + r16]      = (acc10[r] + bj0) * LOG2E2;
      Uh2[(size_t)(row0 + 16) * 256 + n0 + 16 + r16] = (acc11[r] + bj1) * LOG2E2;
    }
  }
}

// ---------------------------------------------------------------------------
// Fused attention. 512 blocks = (b:16)x(sg:32), 2 s-rows/block, 512 thr.
// Score: thread = (s:2, dg:8, t4:32); coalesced Wv2T float4 loads over t.
// Softmax over t: threads<256, wave shuffle + 2-wave LDS combine.
// Context: thread = f (512); fp32 v, broadcast beta, 2 s-rows per v read.
// ---------------------------------------------------------------------------
__global__ __launch_bounds__(512) void attn_fused_kernel(
    const float* __restrict__ Wv2T, const float* __restrict__ Uh2,
    const float* __restrict__ wg, const float* __restrict__ v,
    float* __restrict__ u) {
  __shared__ float UhS[2 * 256];
  __shared__ float wS[256];
  __shared__ float pS[8 * 2 * 128];   // [dg][s][t]
  __shared__ float bS[2 * 128];
  __shared__ float mW[4];
  __shared__ float sW[4];

  const int tid = threadIdx.x;
  const int b   = blockIdx.x >> 5;
  const int sg  = blockIdx.x & 31;
  const int s0  = sg * 2;

  // ---- stage Uh (2x256) and w (256) ----
  if (tid < 128) {
    const int row = tid >> 6, q4 = (tid & 63) << 2;
    *(float4*)&UhS[row * 256 + q4] =
        *(const float4*)&Uh2[(size_t)(b * 64 + s0 + row) * 256 + q4];
  } else if (tid < 192) {
    const int q4 = (tid - 128) << 2;
    *(float4*)&wS[q4] = *(const float4*)&wg[q4];
  }
  __syncthreads();

  // ---- scores: thread = (s, dg, t4); 32 d x 4 t ----
  {
    const int t4 = tid & 31;
    const int dg = (tid >> 5) & 7;
    const int s  = tid >> 8;      // 0..1
    const float* wvb = Wv2T + (size_t)b * 32768 + (size_t)dg * 32 * 128 + t4 * 4;
    const float4* uhq = (const float4*)&UhS[s * 256 + dg * 32];
    const float4* wq  = (const float4*)&wS[dg * 32];
    float4 acc = {0.f, 0.f, 0.f, 0.f};
#pragma unroll
    for (int jq = 0; jq < 8; jq++) {
      float4 uh4 = uhq[jq];
      float4 w4  = wq[jq];
#pragma unroll
      for (int jj = 0; jj < 4; jj++) {
        float4 a  = *(const float4*)(wvb + (jq * 4 + jj) * 128);
        float uh = (&uh4.x)[jj];
        float ww = (&w4.x)[jj];
        acc.x = fmaf(ww, fast_rcp(fast_exp2(a.x + uh) + 1.0f), acc.x);
        acc.y = fmaf(ww, fast_rcp(fast_exp2(a.y + uh) + 1.0f), acc.y);
        acc.z = fmaf(ww, fast_rcp(fast_exp2(a.z + uh) + 1.0f), acc.z);
        acc.w = fmaf(ww, fast_rcp(fast_exp2(a.w + uh) + 1.0f), acc.w);
      }
    }
    *(float4*)&pS[(dg * 2 + s) * 128 + t4 * 4] = acc;
  }
  __syncthreads();

  // ---- reduce over dg + softmax over t (threads < 256) ----
  float qv = 0.0f, ev = 0.0f;
  const int wvid = tid >> 6, lane = tid & 63;
  if (tid < 256) {
    const int s_l = tid >> 7, t = tid & 127;
    float ssum = 0.0f;
#pragma unroll
    for (int dg = 0; dg < 8; dg++) ssum += pS[(dg * 2 + s_l) * 128 + t];
    qv = ssum * (-LOG2E2);   // log2-domain score
    float m = qv;
#pragma unroll
    for (int off = 32; off > 0; off >>= 1) m = fmaxf(m, __shfl_xor(m, off, 64));
    if (lane == 0) mW[wvid] = m;
  }
  __syncthreads();
  if (tid < 256) {
    float m = fmaxf(mW[wvid], mW[wvid ^ 1]);
    ev = fast_exp2(qv - m);
    float ssum = ev;
#pragma unroll
    for (int off = 32; off > 0; off >>= 1) ssum += __shfl_xor(ssum, off, 64);
    if (lane == 0) sW[wvid] = ssum;
  }
  __syncthreads();
  if (tid < 256) {
    const int s_l = tid >> 7, t = tid & 127;
    bS[s_l * 128 + t] = ev * fast_rcp(sW[wvid] + sW[wvid ^ 1]);
  }
  __syncthreads();

  // ---- context: thread = f (512); fp32 v, 2 s-rows per v read ----
  const float* vb2 = v + (size_t)b * TV * FF;
  const int f = tid;
  float a0 = 0.f, a1 = 0.f;
#pragma unroll 4
  for (int tg = 0; tg < 128; tg += 4) {
    float4 b0 = *(const float4*)&bS[0 * 128 + tg];
    float4 b1 = *(const float4*)&bS[1 * 128 + tg];
    float v0 = vb2[(tg + 0) * 512 + f];
    float v1 = vb2[(tg + 1) * 512 + f];
    float v2 = vb2[(tg + 2) * 512 + f];
    float v3 = vb2[(tg + 3) * 512 + f];
    a0 = fmaf(b0.x, v0, a0); a0 = fmaf(b0.y, v1, a0);
    a0 = fmaf(b0.z, v2, a0); a0 = fmaf(b0.w, v3, a0);
    a1 = fmaf(b1.x, v0, a1); a1 = fmaf(b1.y, v1, a1);
    a1 = fmaf(b1.z, v2, a1); a1 = fmaf(b1.w, v3, a1);
  }
  float* urow = u + (size_t)(b * 64 + s0) * 512;
  urow[0 * 512 + f] = a0;
  urow[1 * 512 + f] = a1;
}

extern "C" void kernel_launch(void* const* d_in, const int* in_sizes, int n_in,
                              void* d_out, int out_size, void* d_ws, size_t ws_size,
                              hipStream_t stream) {
  const float* v  = (const float*)d_in[0];  // [16,128,512]
  const float* h  = (const float*)d_in[1];  // [16,64,512]
  const float* W  = (const float*)d_in[2];  // [512,256]
  const float* U  = (const float*)d_in[3];  // [512,256]
  const float* bb = (const float*)d_in[4];  // [256]
  const float* w  = (const float*)d_in[5];  // [256,1]
  float* u = (float*)d_out;                 // [16,64,512]

  float* Wv2T = (float*)d_ws;                      // [16][256][128] f32 prescaled
  float* Uh2  = Wv2T + (size_t)2048 * 256;         // [1024,256] f32 prescaled

  mfma_gemm_kernel<<<192, 256, 0, stream>>>(v, h, W, U, bb, Wv2T, Uh2);
  attn_fused_kernel<<<512, 512, 0, stream>>>(Wv2T, Uh2, w, v, u);
}

// Round 8
// 96.871 us; speedup vs baseline: 1.0212x; 1.0212x over previous
//
#include <hip/hip_runtime.h>
#include <hip/hip_bf16.h>

// Problem constants: B=16, TV=128, TH=64, F=512, H=512, D=256
#define BB 16
#define TV 128
#define TH 64
#define FF 512
#define HH 512
#define DD 256

#define LOG2E2 2.8853900817779268f   // 2*log2(e): exp2(LOG2E2*x) = e^{2x}

typedef __attribute__((ext_vector_type(8))) short bf16x8;   // 8 bf16 = 4 VGPRs
typedef __attribute__((ext_vector_type(4))) float f32x4;

__device__ __forceinline__ float fast_exp2(float x) {
#if __has_builtin(__builtin_amdgcn_exp2f)
  return __builtin_amdgcn_exp2f(x);
#else
  return __expf(x * 0.6931471805599453f);
#endif
}
__device__ __forceinline__ float fast_rcp(float x) {
#if __has_builtin(__builtin_amdgcn_rcpf)
  return __builtin_amdgcn_rcpf(x);
#else
  return 1.0f / x;
#endif
}
__device__ __forceinline__ unsigned short f2bf(float x) {  // RNE fp32->bf16
  union { float f; unsigned u; } a; a.f = x;
  unsigned r = a.u + 0x7fffu + ((a.u >> 16) & 1u);
  return (unsigned short)(r >> 16);
}

// ---------------------------------------------------------------------------
// Convert kernel: v,h -> bf16 (row-major); W,U -> bf16 TRANSPOSED ([n][k]).
// (R5 configuration — measured best.)
// ---------------------------------------------------------------------------
#define NT_V 262144
#define NT_H 131072
#define NT_W 32768
__global__ __launch_bounds__(256) void convert_kernel(
    const float* __restrict__ v, const float* __restrict__ h,
    const float* __restrict__ W, const float* __restrict__ U,
    unsigned short* __restrict__ vb, unsigned short* __restrict__ hb,
    unsigned short* __restrict__ WT, unsigned short* __restrict__ UT) {
  int task = blockIdx.x * 256 + threadIdx.x;
  if (task < NT_V) {
    float4 x = ((const float4*)v)[task];
    ushort4 o = make_ushort4(f2bf(x.x), f2bf(x.y), f2bf(x.z), f2bf(x.w));
    *(ushort4*)&vb[(size_t)task * 4] = o;
  } else if (task < NT_V + NT_H) {
    int t2 = task - NT_V;
    float4 x = ((const float4*)h)[t2];
    ushort4 o = make_ushort4(f2bf(x.x), f2bf(x.y), f2bf(x.z), f2bf(x.w));
    *(ushort4*)&hb[(size_t)t2 * 4] = o;
  } else {
    int t2 = task - NT_V - NT_H;
    const float* S;
    unsigned short* Dt;
    if (t2 < NT_W) { S = W; Dt = WT; } else { S = U; Dt = UT; t2 -= NT_W; }
    int n = t2 & 255, k4 = t2 >> 8;           // k4 in [0,128)
    float a0 = S[(k4 * 4 + 0) * 256 + n];     // coalesced over n
    float a1 = S[(k4 * 4 + 1) * 256 + n];
    float a2 = S[(k4 * 4 + 2) * 256 + n];
    float a3 = S[(k4 * 4 + 3) * 256 + n];
    ushort4 o = make_ushort4(f2bf(a0), f2bf(a1), f2bf(a2), f2bf(a3));
    *(ushort4*)&Dt[(size_t)n * 512 + k4 * 4] = o;
  }
}

// ---------------------------------------------------------------------------
// MFMA GEMM, no LDS, no barriers. 384 blocks * 128 thr (2 waves).
// (R5 configuration — measured best.)
//   blocks [0,256):   Wv2T[b][d][t] = (v @ W)^T-per-b * LOG2E2   (transposed)
//   blocks [256,384): Uh2[m][d]     = (h @ U + b) * LOG2E2       (row-major)
// Wave tile 32m x 32n x 512k via 2x2 of mfma_f32_16x16x32_bf16.
// C/D: col = l&15, row = (l>>4)*4 + reg   (m89-verified)
// ---------------------------------------------------------------------------
__global__ __launch_bounds__(128) void mfma_gemm_kernel(
    const unsigned short* __restrict__ Av, const unsigned short* __restrict__ Ah,
    const unsigned short* __restrict__ WT, const unsigned short* __restrict__ UT,
    const float* __restrict__ bias, float* __restrict__ Wv2T,
    float* __restrict__ Uh2) {
  const int bid = blockIdx.x;
  const unsigned short* A;
  const unsigned short* BT;
  int mt, nt;
  bool is_wv;
  if (bid < 256) {
    A = Av; BT = WT; is_wv = true;
    mt = bid >> 3; nt = bid & 7;
  } else {
    const int b2 = bid - 256;
    A = Ah; BT = UT; is_wv = false;
    mt = b2 >> 3; nt = b2 & 7;
  }
  const int wv   = threadIdx.x >> 6;   // 0..1
  const int lane = threadIdx.x & 63;
  const int m0   = mt * 64 + wv * 32;
  const int n0   = nt * 32;
  const int r16  = lane & 15;
  const int quad = lane >> 4;

  const unsigned short* a0p = A + (size_t)(m0 + r16) * 512 + quad * 8;
  const unsigned short* a1p = a0p + 16 * 512;
  const unsigned short* b0p = BT + (size_t)(n0 + r16) * 512 + quad * 8;
  const unsigned short* b1p = b0p + 16 * 512;

  f32x4 acc00 = {0.f, 0.f, 0.f, 0.f};
  f32x4 acc01 = {0.f, 0.f, 0.f, 0.f};
  f32x4 acc10 = {0.f, 0.f, 0.f, 0.f};
  f32x4 acc11 = {0.f, 0.f, 0.f, 0.f};

#pragma unroll
  for (int kc = 0; kc < 16; kc++) {
    bf16x8 a0 = *(const bf16x8*)(a0p + kc * 32);
    bf16x8 a1 = *(const bf16x8*)(a1p + kc * 32);
    bf16x8 b0 = *(const bf16x8*)(b0p + kc * 32);
    bf16x8 b1 = *(const bf16x8*)(b1p + kc * 32);
    acc00 = __builtin_amdgcn_mfma_f32_16x16x32_bf16(a0, b0, acc00, 0, 0, 0);
    acc01 = __builtin_amdgcn_mfma_f32_16x16x32_bf16(a0, b1, acc01, 0, 0, 0);
    acc10 = __builtin_amdgcn_mfma_f32_16x16x32_bf16(a1, b0, acc10, 0, 0, 0);
    acc11 = __builtin_amdgcn_mfma_f32_16x16x32_bf16(a1, b1, acc11, 0, 0, 0);
  }

  if (is_wv) {
    // Wv2T[b][d][t], b = m0>>7, t-base = (m0&127) + quad*4 (r contiguous)
    const int bb = m0 >> 7;
    const int tb = (m0 & 127) + quad * 4;
    float* Wb = Wv2T + (size_t)bb * 32768;
    float4 s00, s01, s10, s11;
#pragma unroll
    for (int r = 0; r < 4; r++) {
      (&s00.x)[r] = acc00[r] * LOG2E2;
      (&s01.x)[r] = acc01[r] * LOG2E2;
      (&s10.x)[r] = acc10[r] * LOG2E2;
      (&s11.x)[r] = acc11[r] * LOG2E2;
    }
    *(float4*)&Wb[(size_t)(n0 + r16) * 128 + tb]           = s00;
    *(float4*)&Wb[(size_t)(n0 + r16) * 128 + tb + 16]      = s10;
    *(float4*)&Wb[(size_t)(n0 + 16 + r16) * 128 + tb]      = s01;
    *(float4*)&Wb[(size_t)(n0 + 16 + r16) * 128 + tb + 16] = s11;
  } else {
    const float bj0 = bias[n0 + r16];
    const float bj1 = bias[n0 + 16 + r16];
#pragma unroll
    for (int r = 0; r < 4; r++) {
      const int row0 = m0 + quad * 4 + r;
      Uh2[(size_t)row0 * 256 + n0 + r16]             = (acc00[r] + bj0) * LOG2E2;
      Uh2[(size_t)row0 * 256 + n0 + 16 + r16]        = (acc01[r] + bj1) * LOG2E2;
      Uh2[(size_t)(row0 + 16) * 256 + n0 + r16]      = (acc10[r] + bj0) * LOG2E2;
      Uh2[(size_t)(row0 + 16) * 256 + n0 + 16 + r16] = (acc11[r] + bj1) * LOG2E2;
    }
  }
}

// ---------------------------------------------------------------------------
// Fused attention. 256 blocks = (b:16)x(sg:16), 4 s-rows/block, 1024 thr.
// (R5 structure; score phase de-duplicates Wv loads across s.)
// Score: thread = (dg:32, t4:32); loads its 8 d-float4s ONCE, accumulates
//   all 4 s-rows from them (Uh/w via LDS broadcast). 128 sigmoids/thread.
//   Partials -> pS[dg][s][t] (64 KB), b128 conflict-free writes.
// Reduce+softmax over t: threads<512, 32 b32 reads (stride-512, no conflict),
//   wave shuffle + 2-wave LDS combine.
// Context: thread = (f:512, sh:2), coalesced fp32 v reads, broadcast beta.
// ---------------------------------------------------------------------------
__global__ __launch_bounds__(1024) void attn_fused_kernel(
    const float* __restrict__ Wv2T, const float* __restrict__ Uh2,
    const float* __restrict__ wg, const float* __restrict__ v,
    float* __restrict__ u) {
  __shared__ float UhS[4 * 256];
  __shared__ float wS[256];
  __shared__ float pS[32 * 4 * 128];   // [dg][s][t] = 64 KB
  __shared__ float bS[4 * 128];
  __shared__ float mW[8];
  __shared__ float sW[8];

  const int tid = threadIdx.x;
  const int b   = blockIdx.x >> 4;
  const int sg  = blockIdx.x & 15;
  const int s0  = sg * 4;

  // ---- stage Uh (4x256) and w (256) ----
  if (tid < 256) {
    const int row = tid >> 6, q4 = (tid & 63) << 2;
    *(float4*)&UhS[row * 256 + q4] =
        *(const float4*)&Uh2[(size_t)(b * 64 + s0 + row) * 256 + q4];
  } else if (tid < 320) {
    const int q4 = (tid - 256) << 2;
    *(float4*)&wS[q4] = *(const float4*)&wg[q4];
  }
  __syncthreads();

  // ---- scores: thread = (dg:32, t4:32); 8 d x 4 t x 4 s ----
  {
    const int t4 = tid & 31;
    const int dg = tid >> 5;     // 0..31
    const float* wvb = Wv2T + (size_t)b * 32768 + (size_t)dg * 8 * 128 + t4 * 4;
    float4 acc0 = {0.f, 0.f, 0.f, 0.f};
    float4 acc1 = {0.f, 0.f, 0.f, 0.f};
    float4 acc2 = {0.f, 0.f, 0.f, 0.f};
    float4 acc3 = {0.f, 0.f, 0.f, 0.f};
#pragma unroll
    for (int j = 0; j < 8; j++) {
      float4 a  = *(const float4*)(wvb + j * 128);   // 4 t's, one d — loaded ONCE
      float ww  = wS[dg * 8 + j];
      float uh0 = UhS[0 * 256 + dg * 8 + j];
      float uh1 = UhS[1 * 256 + dg * 8 + j];
      float uh2 = UhS[2 * 256 + dg * 8 + j];
      float uh3 = UhS[3 * 256 + dg * 8 + j];
      acc0.x = fmaf(ww, fast_rcp(fast_exp2(a.x + uh0) + 1.0f), acc0.x);
      acc0.y = fmaf(ww, fast_rcp(fast_exp2(a.y + uh0) + 1.0f), acc0.y);
      acc0.z = fmaf(ww, fast_rcp(fast_exp2(a.z + uh0) + 1.0f), acc0.z);
      acc0.w = fmaf(ww, fast_rcp(fast_exp2(a.w + uh0) + 1.0f), acc0.w);
      acc1.x = fmaf(ww, fast_rcp(fast_exp2(a.x + uh1) + 1.0f), acc1.x);
      acc1.y = fmaf(ww, fast_rcp(fast_exp2(a.y + uh1) + 1.0f), acc1.y);
      acc1.z = fmaf(ww, fast_rcp(fast_exp2(a.z + uh1) + 1.0f), acc1.z);
      acc1.w = fmaf(ww, fast_rcp(fast_exp2(a.w + uh1) + 1.0f), acc1.w);
      acc2.x = fmaf(ww, fast_rcp(fast_exp2(a.x + uh2) + 1.0f), acc2.x);
      acc2.y = fmaf(ww, fast_rcp(fast_exp2(a.y + uh2) + 1.0f), acc2.y);
      acc2.z = fmaf(ww, fast_rcp(fast_exp2(a.z + uh2) + 1.0f), acc2.z);
      acc2.w = fmaf(ww, fast_rcp(fast_exp2(a.w + uh2) + 1.0f), acc2.w);
      acc3.x = fmaf(ww, fast_rcp(fast_exp2(a.x + uh3) + 1.0f), acc3.x);
      acc3.y = fmaf(ww, fast_rcp(fast_exp2(a.y + uh3) + 1.0f), acc3.y);
      acc3.z = fmaf(ww, fast_rcp(fast_exp2(a.z + uh3) + 1.0f), acc3.z);
      acc3.w = fmaf(ww, fast_rcp(fast_exp2(a.w + uh3) + 1.0f), acc3.w);
    }
    *(float4*)&pS[(dg * 4 + 0) * 128 + t4 * 4] = acc0;
    *(float4*)&pS[(dg * 4 + 1) * 128 + t4 * 4] = acc1;
    *(float4*)&pS[(dg * 4 + 2) * 128 + t4 * 4] = acc2;
    *(float4*)&pS[(dg * 4 + 3) * 128 + t4 * 4] = acc3;
  }
  __syncthreads();

  // ---- reduce over dg + softmax over t (threads < 512) ----
  float qv = 0.0f, ev = 0.0f;
  const int wvid = tid >> 6, lane = tid & 63;
  if (tid < 512) {
    const int s_l = tid >> 7, t = tid & 127;
    float ssum = 0.0f;
#pragma unroll
    for (int dg = 0; dg < 32; dg++) ssum += pS[(dg * 4 + s_l) * 128 + t];
    qv = ssum * (-LOG2E2);   // log2-domain score
    float m = qv;
#pragma unroll
    for (int off = 32; off > 0; off >>= 1) m = fmaxf(m, __shfl_xor(m, off, 64));
    if (lane == 0) mW[wvid] = m;
  }
  __syncthreads();
  if (tid < 512) {
    float m = fmaxf(mW[wvid], mW[wvid ^ 1]);
    ev = fast_exp2(qv - m);
    float ssum = ev;
#pragma unroll
    for (int off = 32; off > 0; off >>= 1) ssum += __shfl_xor(ssum, off, 64);
    if (lane == 0) sW[wvid] = ssum;
  }
  __syncthreads();
  if (tid < 512) {
    const int s_l = tid >> 7, t = tid & 127;
    bS[s_l * 128 + t] = ev * fast_rcp(sW[wvid] + sW[wvid ^ 1]);
  }
  __syncthreads();

  // ---- context: thread = (f:512, sh:2); 2 s-rows each ----
  const float* vb2 = v + (size_t)b * TV * FF;
  const int f  = tid & 511;
  const int sh = tid >> 9;
  float a0 = 0.f, a1 = 0.f;
#pragma unroll 4
  for (int tg = 0; tg < 128; tg += 4) {
    float4 b0 = *(const float4*)&bS[(sh * 2 + 0) * 128 + tg];
    float4 b1 = *(const float4*)&bS[(sh * 2 + 1) * 128 + tg];
    float v0 = vb2[(tg + 0) * 512 + f];
    float v1 = vb2[(tg + 1) * 512 + f];
    float v2 = vb2[(tg + 2) * 512 + f];
    float v3 = vb2[(tg + 3) * 512 + f];
    a0 = fmaf(b0.x, v0, a0); a0 = fmaf(b0.y, v1, a0);
    a0 = fmaf(b0.z, v2, a0); a0 = fmaf(b0.w, v3, a0);
    a1 = fmaf(b1.x, v0, a1); a1 = fmaf(b1.y, v1, a1);
    a1 = fmaf(b1.z, v2, a1); a1 = fmaf(b1.w, v3, a1);
  }
  float* urow = u + (size_t)(b * 64 + s0 + sh * 2) * 512;
  urow[0 * 512 + f] = a0;
  urow[1 * 512 + f] = a1;
}

extern "C" void kernel_launch(void* const* d_in, const int* in_sizes, int n_in,
                              void* d_out, int out_size, void* d_ws, size_t ws_size,
                              hipStream_t stream) {
  const float* v  = (const float*)d_in[0];  // [16,128,512]
  const float* h  = (const float*)d_in[1];  // [16,64,512]
  const float* W  = (const float*)d_in[2];  // [512,256]
  const float* U  = (const float*)d_in[3];  // [512,256]
  const float* bb = (const float*)d_in[4];  // [256]
  const float* w  = (const float*)d_in[5];  // [256,1]
  float* u = (float*)d_out;                 // [16,64,512]

  float* Wv2T = (float*)d_ws;                      // [16][256][128] f32 prescaled
  float* Uh2  = Wv2T + (size_t)2048 * 256;         // [1024,256] f32 prescaled
  unsigned short* vb16 = (unsigned short*)(Uh2 + (size_t)1024 * 256);
  unsigned short* hb16 = vb16 + (size_t)2048 * 512;  // bf16 copies
  unsigned short* WT   = hb16 + (size_t)1024 * 512;  // [256][512] bf16 (W^T)
  unsigned short* UT   = WT + (size_t)256 * 512;     // [256][512] bf16 (U^T)

  convert_kernel<<<1792, 256, 0, stream>>>(v, h, W, U, vb16, hb16, WT, UT);
  mfma_gemm_kernel<<<384, 128, 0, stream>>>(vb16, hb16, WT, UT, bb, Wv2T, Uh2);
  attn_fused_kernel<<<256, 1024, 0, stream>>>(Wv2T, Uh2, w, v, u);
}

// Round 9
// 93.317 us; speedup vs baseline: 1.0601x; 1.0381x over previous
//
#include <hip/hip_runtime.h>
#include <hip/hip_bf16.h>

// Problem constants: B=16, TV=128, TH=64, F=512, H=512, D=256
#define BB 16
#define TV 128
#define TH 64
#define FF 512
#define HH 512
#define DD 256

#define LOG2E2 2.8853900817779268f   // 2*log2(e): exp2(LOG2E2*x) = e^{2x}

typedef __attribute__((ext_vector_type(8))) short bf16x8;   // 8 bf16 = 4 VGPRs
typedef __attribute__((ext_vector_type(4))) float f32x4;

__device__ __forceinline__ float fast_exp2(float x) {
#if __has_builtin(__builtin_amdgcn_exp2f)
  return __builtin_amdgcn_exp2f(x);
#else
  return __expf(x * 0.6931471805599453f);
#endif
}
__device__ __forceinline__ float fast_rcp(float x) {
#if __has_builtin(__builtin_amdgcn_rcpf)
  return __builtin_amdgcn_rcpf(x);
#else
  return 1.0f / x;
#endif
}
__device__ __forceinline__ unsigned short f2bf(float x) {  // RNE fp32->bf16
  union { float f; unsigned u; } a; a.f = x;
  unsigned r = a.u + 0x7fffu + ((a.u >> 16) & 1u);
  return (unsigned short)(r >> 16);
}

// ---------------------------------------------------------------------------
// Convert kernel: v,h -> bf16 (row-major); W,U -> bf16 TRANSPOSED ([n][k]).
// (R5 configuration — measured best, 92.9 us total.)
// ---------------------------------------------------------------------------
#define NT_V 262144
#define NT_H 131072
#define NT_W 32768
__global__ __launch_bounds__(256) void convert_kernel(
    const float* __restrict__ v, const float* __restrict__ h,
    const float* __restrict__ W, const float* __restrict__ U,
    unsigned short* __restrict__ vb, unsigned short* __restrict__ hb,
    unsigned short* __restrict__ WT, unsigned short* __restrict__ UT) {
  int task = blockIdx.x * 256 + threadIdx.x;
  if (task < NT_V) {
    float4 x = ((const float4*)v)[task];
    ushort4 o = make_ushort4(f2bf(x.x), f2bf(x.y), f2bf(x.z), f2bf(x.w));
    *(ushort4*)&vb[(size_t)task * 4] = o;
  } else if (task < NT_V + NT_H) {
    int t2 = task - NT_V;
    float4 x = ((const float4*)h)[t2];
    ushort4 o = make_ushort4(f2bf(x.x), f2bf(x.y), f2bf(x.z), f2bf(x.w));
    *(ushort4*)&hb[(size_t)t2 * 4] = o;
  } else {
    int t2 = task - NT_V - NT_H;
    const float* S;
    unsigned short* Dt;
    if (t2 < NT_W) { S = W; Dt = WT; } else { S = U; Dt = UT; t2 -= NT_W; }
    int n = t2 & 255, k4 = t2 >> 8;           // k4 in [0,128)
    float a0 = S[(k4 * 4 + 0) * 256 + n];     // coalesced over n
    float a1 = S[(k4 * 4 + 1) * 256 + n];
    float a2 = S[(k4 * 4 + 2) * 256 + n];
    float a3 = S[(k4 * 4 + 3) * 256 + n];
    ushort4 o = make_ushort4(f2bf(a0), f2bf(a1), f2bf(a2), f2bf(a3));
    *(ushort4*)&Dt[(size_t)n * 512 + k4 * 4] = o;
  }
}

// ---------------------------------------------------------------------------
// MFMA GEMM, no LDS, no barriers. 384 blocks * 128 thr (2 waves).
//   blocks [0,256):   Wv2T[b][d][t] = (v @ W)^T-per-b * LOG2E2   (transposed)
//   blocks [256,384): Uh2[m][d]     = (h @ U + b) * LOG2E2       (row-major)
// Wave tile: 32m x 32n x 512k via 2x2 of mfma_f32_16x16x32_bf16.
// C/D: col = l&15, row = (l>>4)*4 + reg   (m89-verified)
// ---------------------------------------------------------------------------
__global__ __launch_bounds__(128) void mfma_gemm_kernel(
    const unsigned short* __restrict__ Av, const unsigned short* __restrict__ Ah,
    const unsigned short* __restrict__ WT, const unsigned short* __restrict__ UT,
    const float* __restrict__ bias, float* __restrict__ Wv2T,
    float* __restrict__ Uh2) {
  const int bid = blockIdx.x;
  const unsigned short* A;
  const unsigned short* BT;
  int mt, nt;
  bool is_wv;
  if (bid < 256) {
    A = Av; BT = WT; is_wv = true;
    mt = bid >> 3; nt = bid & 7;
  } else {
    const int b2 = bid - 256;
    A = Ah; BT = UT; is_wv = false;
    mt = b2 >> 3; nt = b2 & 7;
  }
  const int wv   = threadIdx.x >> 6;   // 0..1
  const int lane = threadIdx.x & 63;
  const int m0   = mt * 64 + wv * 32;
  const int n0   = nt * 32;
  const int r16  = lane & 15;
  const int quad = lane >> 4;

  const unsigned short* a0p = A + (size_t)(m0 + r16) * 512 + quad * 8;
  const unsigned short* a1p = a0p + 16 * 512;
  const unsigned short* b0p = BT + (size_t)(n0 + r16) * 512 + quad * 8;
  const unsigned short* b1p = b0p + 16 * 512;

  f32x4 acc00 = {0.f, 0.f, 0.f, 0.f};
  f32x4 acc01 = {0.f, 0.f, 0.f, 0.f};
  f32x4 acc10 = {0.f, 0.f, 0.f, 0.f};
  f32x4 acc11 = {0.f, 0.f, 0.f, 0.f};

#pragma unroll
  for (int kc = 0; kc < 16; kc++) {
    bf16x8 a0 = *(const bf16x8*)(a0p + kc * 32);
    bf16x8 a1 = *(const bf16x8*)(a1p + kc * 32);
    bf16x8 b0 = *(const bf16x8*)(b0p + kc * 32);
    bf16x8 b1 = *(const bf16x8*)(b1p + kc * 32);
    acc00 = __builtin_amdgcn_mfma_f32_16x16x32_bf16(a0, b0, acc00, 0, 0, 0);
    acc01 = __builtin_amdgcn_mfma_f32_16x16x32_bf16(a0, b1, acc01, 0, 0, 0);
    acc10 = __builtin_amdgcn_mfma_f32_16x16x32_bf16(a1, b0, acc10, 0, 0, 0);
    acc11 = __builtin_amdgcn_mfma_f32_16x16x32_bf16(a1, b1, acc11, 0, 0, 0);
  }

  if (is_wv) {
    // Wv2T[b][d][t], b = m0>>7, t-base = (m0&127) + quad*4 (r contiguous)
    const int bb = m0 >> 7;
    const int tb = (m0 & 127) + quad * 4;
    float* Wb = Wv2T + (size_t)bb * 32768;
    float4 s00, s01, s10, s11;
#pragma unroll
    for (int r = 0; r < 4; r++) {
      (&s00.x)[r] = acc00[r] * LOG2E2;
      (&s01.x)[r] = acc01[r] * LOG2E2;
      (&s10.x)[r] = acc10[r] * LOG2E2;
      (&s11.x)[r] = acc11[r] * LOG2E2;
    }
    *(float4*)&Wb[(size_t)(n0 + r16) * 128 + tb]           = s00;
    *(float4*)&Wb[(size_t)(n0 + r16) * 128 + tb + 16]      = s10;
    *(float4*)&Wb[(size_t)(n0 + 16 + r16) * 128 + tb]      = s01;
    *(float4*)&Wb[(size_t)(n0 + 16 + r16) * 128 + tb + 16] = s11;
  } else {
    const float bj0 = bias[n0 + r16];
    const float bj1 = bias[n0 + 16 + r16];
#pragma unroll
    for (int r = 0; r < 4; r++) {
      const int row0 = m0 + quad * 4 + r;
      Uh2[(size_t)row0 * 256 + n0 + r16]             = (acc00[r] + bj0) * LOG2E2;
      Uh2[(size_t)row0 * 256 + n0 + 16 + r16]        = (acc01[r] + bj1) * LOG2E2;
      Uh2[(size_t)(row0 + 16) * 256 + n0 + r16]      = (acc10[r] + bj0) * LOG2E2;
      Uh2[(size_t)(row0 + 16) * 256 + n0 + 16 + r16] = (acc11[r] + bj1) * LOG2E2;
    }
  }
}

// ---------------------------------------------------------------------------
// Fused attention. 256 blocks = (b:16)x(sg:16), 4 s-rows/block, 1024 thr.
// Score: thread = (s:4, dg:8, t4:32); per d it loads Wv2T[d][4t] as float4
//   (lanes t4 consecutive -> contiguous 512 B segments), 4 sigmoids/d,
//   32 d per thread; partials -> pS[s][dg][t] (16 KB), 8-way reduce.
// Softmax over t: threads<512, wave shuffle + 2-wave LDS combine.
// Context: thread = (f:512, sh:2), coalesced fp32 v reads, broadcast beta.
// ---------------------------------------------------------------------------
__global__ __launch_bounds__(1024) void attn_fused_kernel(
    const float* __restrict__ Wv2T, const float* __restrict__ Uh2,
    const float* __restrict__ wg, const float* __restrict__ v,
    float* __restrict__ u) {
  __shared__ float UhS[4 * 256];
  __shared__ float wS[256];
  __shared__ float pS[4 * 1024];   // [s][dg][t]
  __shared__ float bS[4 * 128];
  __shared__ float mW[8];
  __shared__ float sW[8];

  const int tid = threadIdx.x;
  const int b   = blockIdx.x >> 4;
  const int sg  = blockIdx.x & 15;
  const int s0  = sg * 4;

  // ---- stage Uh (4x256) and w (256) ----
  if (tid < 256) {
    const int row = tid >> 6, q4 = (tid & 63) << 2;
    *(float4*)&UhS[row * 256 + q4] =
        *(const float4*)&Uh2[(size_t)(b * 64 + s0 + row) * 256 + q4];
  } else if (tid < 320) {
    const int q4 = (tid - 256) << 2;
    *(float4*)&wS[q4] = *(const float4*)&wg[q4];
  }
  __syncthreads();

  // ---- scores: thread = (s, dg, t4); 32 d x 4 t ----
  {
    const int t4 = tid & 31;
    const int dg = (tid >> 5) & 7;
    const int s  = tid >> 8;
    const float* wvb = Wv2T + (size_t)b * 32768 + (size_t)dg * 32 * 128 + t4 * 4;
    const float* uhp = &UhS[s * 256 + dg * 32];
    const float* wp  = &wS[dg * 32];
    float4 acc = {0.f, 0.f, 0.f, 0.f};
#pragma unroll 8
    for (int j = 0; j < 32; j++) {
      float4 a  = *(const float4*)(wvb + j * 128);
      float uh = uhp[j];
      float ww = wp[j];
      acc.x = fmaf(ww, fast_rcp(fast_exp2(a.x + uh) + 1.0f), acc.x);
      acc.y = fmaf(ww, fast_rcp(fast_exp2(a.y + uh) + 1.0f), acc.y);
      acc.z = fmaf(ww, fast_rcp(fast_exp2(a.z + uh) + 1.0f), acc.z);
      acc.w = fmaf(ww, fast_rcp(fast_exp2(a.w + uh) + 1.0f), acc.w);
    }
    *(float4*)&pS[s * 1024 + dg * 128 + t4 * 4] = acc;
  }
  __syncthreads();

  // ---- reduce over dg + softmax over t (threads < 512) ----
  float qv = 0.0f, ev = 0.0f;
  const int wvid = tid >> 6, lane = tid & 63;
  if (tid < 512) {
    const int s_l = tid >> 7, t = tid & 127;
    float ssum = 0.0f;
#pragma unroll
    for (int dg = 0; dg < 8; dg++) ssum += pS[s_l * 1024 + dg * 128 + t];
    qv = ssum * (-LOG2E2);   // log2-domain score
    float m = qv;
#pragma unroll
    for (int off = 32; off > 0; off >>= 1) m = fmaxf(m, __shfl_xor(m, off, 64));
    if (lane == 0) mW[wvid] = m;
  }
  __syncthreads();
  if (tid < 512) {
    float m = fmaxf(mW[wvid], mW[wvid ^ 1]);
    ev = fast_exp2(qv - m);
    float ssum = ev;
#pragma unroll
    for (int off = 32; off > 0; off >>= 1) ssum += __shfl_xor(ssum, off, 64);
    if (lane == 0) sW[wvid] = ssum;
  }
  __syncthreads();
  if (tid < 512) {
    const int s_l = tid >> 7, t = tid & 127;
    bS[s_l * 128 + t] = ev * fast_rcp(sW[wvid] + sW[wvid ^ 1]);
  }
  __syncthreads();

  // ---- context: thread = (f:512, sh:2); 2 s-rows each ----
  const float* vb2 = v + (size_t)b * TV * FF;
  const int f  = tid & 511;
  const int sh = tid >> 9;
  float a0 = 0.f, a1 = 0.f;
#pragma unroll 4
  for (int tg = 0; tg < 128; tg += 4) {
    float4 b0 = *(const float4*)&bS[(sh * 2 + 0) * 128 + tg];
    float4 b1 = *(const float4*)&bS[(sh * 2 + 1) * 128 + tg];
    float v0 = vb2[(tg + 0) * 512 + f];
    float v1 = vb2[(tg + 1) * 512 + f];
    float v2 = vb2[(tg + 2) * 512 + f];
    float v3 = vb2[(tg + 3) * 512 + f];
    a0 = fmaf(b0.x, v0, a0); a0 = fmaf(b0.y, v1, a0);
    a0 = fmaf(b0.z, v2, a0); a0 = fmaf(b0.w, v3, a0);
    a1 = fmaf(b1.x, v0, a1); a1 = fmaf(b1.y, v1, a1);
    a1 = fmaf(b1.z, v2, a1); a1 = fmaf(b1.w, v3, a1);
  }
  float* urow = u + (size_t)(b * 64 + s0 + sh * 2) * 512;
  urow[0 * 512 + f] = a0;
  urow[1 * 512 + f] = a1;
}

extern "C" void kernel_launch(void* const* d_in, const int* in_sizes, int n_in,
                              void* d_out, int out_size, void* d_ws, size_t ws_size,
                              hipStream_t stream) {
  const float* v  = (const float*)d_in[0];  // [16,128,512]
  const float* h  = (const float*)d_in[1];  // [16,64,512]
  const float* W  = (const float*)d_in[2];  // [512,256]
  const float* U  = (const float*)d_in[3];  // [512,256]
  const float* bb = (const float*)d_in[4];  // [256]
  const float* w  = (const float*)d_in[5];  // [256,1]
  float* u = (float*)d_out;                 // [16,64,512]

  float* Wv2T = (float*)d_ws;                      // [16][256][128] f32 prescaled
  float* Uh2  = Wv2T + (size_t)2048 * 256;         // [1024,256] f32 prescaled
  unsigned short* vb16 = (unsigned short*)(Uh2 + (size_t)1024 * 256);
  unsigned short* hb16 = vb16 + (size_t)2048 * 512;  // bf16 copies
  unsigned short* WT   = hb16 + (size_t)1024 * 512;  // [256][512] bf16 (W^T)
  unsigned short* UT   = WT + (size_t)256 * 512;     // [256][512] bf16 (U^T)

  convert_kernel<<<1792, 256, 0, stream>>>(v, h, W, U, vb16, hb16, WT, UT);
  mfma_gemm_kernel<<<384, 128, 0, stream>>>(vb16, hb16, WT, UT, bb, Wv2T, Uh2);
  attn_fused_kernel<<<256, 1024, 0, stream>>>(Wv2T, Uh2, w, v, u);
}